// Round 11
// baseline (522.316 us; speedup 1.0000x reference)
//
#include <hip/hip_runtime.h>
#include <hip/hip_bf16.h>

#define N_NODES 50000
#define N_EDGES 400000
#define NFEAT 128
#define N_REL 500
#define DIM2 256
#define ALPHA_ 0.2f
#define NB_SCAN 98          // ceil(50000/512)
#define BK 32
#define PADK 40

typedef __attribute__((ext_vector_type(4))) float f32x4;
typedef __attribute__((ext_vector_type(8))) short bf16x8;

__device__ __forceinline__ unsigned short f2bf(float x) {
    union { float f; unsigned int u; } v; v.f = x;
    unsigned int r = v.u + 0x7FFFu + ((v.u >> 16) & 1u);
    return (unsigned short)(r >> 16);
}
__device__ __forceinline__ float bf2f(unsigned short u) {
    union { float f; unsigned int i; } v; v.i = (unsigned int)u << 16; return v.f;
}
__device__ __forceinline__ float elu_(float v) { return v > 0.f ? v : expm1f(v); }

// ---------------- fused weight prep ----------------
// B2[256][512]: B2[n][k] = a_out[n][(k<256)?256+k:k-256]   (bf16)
// BX[256][384]: BX[c][k] = a_heads[c*384 + (k<128?256+k : k<256?k : k-256)]  (bf16)
// cvec[1536]: [csrc 4x128 | cdst 4x128 | cr 4x128] from a_heads^T a2h
// csd[512]:   [a_s2^T a2o | a_d2^T a2o] from a_out
__global__ void prep_all(const float* __restrict__ a_heads, const float* __restrict__ a_out,
                         const float* __restrict__ a2h, const float* __restrict__ a2o,
                         unsigned short* __restrict__ B2, unsigned short* __restrict__ BX,
                         float* __restrict__ cvec, float* __restrict__ csd) {
    int idx = blockIdx.x * 256 + threadIdx.x;   // 512 blocks x 256
    if (idx < 256 * 512) {
        int n = idx >> 9, k = idx & 511;
        float v = (k < 256) ? a_out[(size_t)n * 768 + 256 + k]
                            : a_out[(size_t)n * 768 + (k - 256)];
        B2[idx] = f2bf(v);
    }
    if (idx < 256 * 384) {
        int c = idx / 384, k = idx % 384;
        int perm = (k < 128) ? 256 + k : (k < 256) ? k : k - 256;
        BX[idx] = f2bf(a_heads[(size_t)c * 384 + perm]);
    }
    if (idx < 512) {
        int k = idx >> 7, j = idx & 127;
        float s1 = 0.f, s2 = 0.f, s3 = 0.f;
        for (int c = 0; c < 64; ++c) {
            float a2 = a2h[k * 64 + c];
            const float* base = a_heads + (size_t)(k * 64 + c) * 384;
            s1 = fmaf(base[j], a2, s1);
            s2 = fmaf(base[128 + j], a2, s2);
            s3 = fmaf(base[256 + j], a2, s3);
        }
        cvec[idx] = s1; cvec[512 + idx] = s2; cvec[1024 + idx] = s3;
    } else if (idx < 1024) {
        int j = idx - 512;
        float s = 0.f, d = 0.f;
        for (int c = 0; c < 256; ++c) {
            float a = a2o[c];
            s = fmaf(a_out[(size_t)c * 768 + j], a, s);
            d = fmaf(a_out[(size_t)c * 768 + 256 + j], a, d);
        }
        csd[j] = s; csd[256 + j] = d;
    }
}

// ---------------- fused relation table: rel2t + st2 ----------------
__global__ __launch_bounds__(256) void rel2fused(const float* __restrict__ relemb,
        const float* __restrict__ W_1, const float* __restrict__ a_out,
        const float* __restrict__ a2o, float* __restrict__ rel2t,
        float* __restrict__ st2) {
    __shared__ float orow[256];
    __shared__ float ws[4];
    int r = blockIdx.x, c = threadIdx.x;
    float s = 0.f;
    const float* re = relemb + (size_t)r * 128;
    for (int k = 0; k < 128; ++k) s = fmaf(re[k], W_1[(size_t)k * 256 + c], s);
    orow[c] = s;
    __syncthreads();
    float t = 0.f;
    const float* ao = a_out + (size_t)c * 768 + 512;
    for (int k = 0; k < 256; ++k) t = fmaf(orow[k], ao[k], t);
    rel2t[(size_t)r * 256 + c] = t;
    float p = t * a2o[c];
#pragma unroll
    for (int off = 32; off; off >>= 1) p += __shfl_xor(p, off);
    if ((c & 63) == 0) ws[c >> 6] = p;
    __syncthreads();
    if (c == 0) st2[r] = ws[0] + ws[1] + ws[2] + ws[3];
}

// ---------------- CSR build ----------------
__global__ void histk(const int* __restrict__ src, int* __restrict__ deg) {
    int e = blockIdx.x * 256 + threadIdx.x;
    if (e < N_EDGES) atomicAdd(&deg[src[e]], 1);
}

__global__ void scan_part(const int* __restrict__ deg, int* __restrict__ rowptr,
                          int* __restrict__ bsum) {
    __shared__ int buf[512];
    int t = threadIdx.x, b = blockIdx.x;
    int i = b * 512 + t;
    int v = (i < N_NODES) ? deg[i] : 0;
    buf[t] = v;
    __syncthreads();
    for (int off = 1; off < 512; off <<= 1) {
        int x = buf[t];
        int y = (t >= off) ? buf[t - off] : 0;
        __syncthreads();
        buf[t] = x + y;
        __syncthreads();
    }
    if (i < N_NODES) rowptr[i] = buf[t] - v;
    if (t == 511) bsum[b] = buf[511];
}

__global__ void scan_tops(int* __restrict__ bsum) {
    if (threadIdx.x == 0) {
        int run = 0;
        for (int b = 0; b < NB_SCAN; ++b) { int v = bsum[b]; bsum[b] = run; run += v; }
    }
}

__global__ void scan_add(int* __restrict__ rowptr, const int* __restrict__ bsum,
                         int* __restrict__ cur) {
    int i = blockIdx.x * 256 + threadIdx.x;
    if (i == 0) rowptr[N_NODES] = N_EDGES;
    if (i < N_NODES) {
        int r = rowptr[i] + bsum[i >> 9];
        rowptr[i] = r;
        cur[i] = r;
    }
}

// also records pos[e] = CSR slot of edge e
__global__ void scatterk(const int* __restrict__ src, const int* __restrict__ dst,
                         const int* __restrict__ etype, int* __restrict__ cur,
                         int* __restrict__ pos, int* __restrict__ dord,
                         int* __restrict__ tord) {
    int e = blockIdx.x * 256 + threadIdx.x;
    if (e < N_EDGES) {
        int p = atomicAdd(&cur[src[e]], 1);
        pos[e] = p;
        dord[p] = dst[e];
        tord[p] = etype[e];
    }
}

// ---------------- per-node score scalars, layer 1 ----------------
__global__ __launch_bounds__(256) void gemv1(const float* __restrict__ ent,
                                             const float* __restrict__ cvec,
                                             float* __restrict__ vs, float* __restrict__ vd) {
    __shared__ float sv[1024];
    int tid = threadIdx.x;
    for (int i = tid; i < 1024; i += 256) sv[i] = cvec[i];
    __syncthreads();
    int l = tid & 63, wv = tid >> 6;
    int n = blockIdx.x * 4 + wv;
    float2 e = *(const float2*)(ent + (size_t)n * 128 + 2 * l);
    float ps0 = e.x * sv[2 * l] + e.y * sv[2 * l + 1];
    float ps1 = e.x * sv[128 + 2 * l] + e.y * sv[128 + 2 * l + 1];
    float ps2 = e.x * sv[256 + 2 * l] + e.y * sv[256 + 2 * l + 1];
    float ps3 = e.x * sv[384 + 2 * l] + e.y * sv[384 + 2 * l + 1];
    float pd0 = e.x * sv[512 + 2 * l] + e.y * sv[512 + 2 * l + 1];
    float pd1 = e.x * sv[640 + 2 * l] + e.y * sv[640 + 2 * l + 1];
    float pd2 = e.x * sv[768 + 2 * l] + e.y * sv[768 + 2 * l + 1];
    float pd3 = e.x * sv[896 + 2 * l] + e.y * sv[896 + 2 * l + 1];
#pragma unroll
    for (int off = 32; off; off >>= 1) {
        ps0 += __shfl_xor(ps0, off); ps1 += __shfl_xor(ps1, off);
        ps2 += __shfl_xor(ps2, off); ps3 += __shfl_xor(ps3, off);
        pd0 += __shfl_xor(pd0, off); pd1 += __shfl_xor(pd1, off);
        pd2 += __shfl_xor(pd2, off); pd3 += __shfl_xor(pd3, off);
    }
    if (l == 0) {
        vs[n * 4 + 0] = ps0; vs[n * 4 + 1] = ps1; vs[n * 4 + 2] = ps2; vs[n * 4 + 3] = ps3;
        vd[n * 4 + 0] = pd0; vd[n * 4 + 1] = pd1; vd[n * 4 + 2] = pd2; vd[n * 4 + 3] = pd3;
    }
}

// ---------------- edge weights + CSR-permuted bf16 edge store ----------
// 4 lanes/edge; writes w4p[pos[e]] and eembp[pos[e]] (bf16)
__global__ __launch_bounds__(256) void edge_w(const float* __restrict__ eemb,
        const int* __restrict__ src, const int* __restrict__ dst,
        const int* __restrict__ pos, const float* __restrict__ vs,
        const float* __restrict__ vd, const float* __restrict__ cvec,
        float* __restrict__ w4p, unsigned short* __restrict__ eembp) {
    __shared__ float crs[512];
    int t = threadIdx.x;
    for (int i = t; i < 512; i += 256) crs[i] = cvec[1024 + i];
    __syncthreads();
    int q = t & 3;
    int e = blockIdx.x * 64 + (t >> 2);
    if (e >= N_EDGES) return;
    const float* ep = eemb + (size_t)e * 128 + q * 32;
    const float* c0p = &crs[q * 32];
    float s0 = 0.f, s1 = 0.f, s2 = 0.f, s3 = 0.f;
    for (int j = 0; j < 32; j += 4) {
        float4 v  = *(const float4*)(ep + j);
        float4 c0 = *(const float4*)(c0p + j);
        float4 c1 = *(const float4*)(c0p + 128 + j);
        float4 c2 = *(const float4*)(c0p + 256 + j);
        float4 c3 = *(const float4*)(c0p + 384 + j);
        s0 = fmaf(v.x, c0.x, s0); s0 = fmaf(v.y, c0.y, s0);
        s0 = fmaf(v.z, c0.z, s0); s0 = fmaf(v.w, c0.w, s0);
        s1 = fmaf(v.x, c1.x, s1); s1 = fmaf(v.y, c1.y, s1);
        s1 = fmaf(v.z, c1.z, s1); s1 = fmaf(v.w, c1.w, s1);
        s2 = fmaf(v.x, c2.x, s2); s2 = fmaf(v.y, c2.y, s2);
        s2 = fmaf(v.z, c2.z, s2); s2 = fmaf(v.w, c2.w, s2);
        s3 = fmaf(v.x, c3.x, s3); s3 = fmaf(v.y, c3.y, s3);
        s3 = fmaf(v.z, c3.z, s3); s3 = fmaf(v.w, c3.w, s3);
    }
    s0 += __shfl_xor(s0, 1); s0 += __shfl_xor(s0, 2);
    s1 += __shfl_xor(s1, 1); s1 += __shfl_xor(s1, 2);
    s2 += __shfl_xor(s2, 1); s2 += __shfl_xor(s2, 2);
    s3 += __shfl_xor(s3, 1); s3 += __shfl_xor(s3, 2);
    int pe = pos[e];
    // bf16 quarter copy to CSR-ordered buffer (L1-hot re-read)
    unsigned short* op = eembp + (size_t)pe * 128 + q * 32;
#pragma unroll
    for (int j = 0; j < 32; j += 8) {
        float4 v0 = *(const float4*)(ep + j);
        float4 v1 = *(const float4*)(ep + j + 4);
        ushort4 u0, u1;
        u0.x = f2bf(v0.x); u0.y = f2bf(v0.y); u0.z = f2bf(v0.z); u0.w = f2bf(v0.w);
        u1.x = f2bf(v1.x); u1.y = f2bf(v1.y); u1.z = f2bf(v1.z); u1.w = f2bf(v1.w);
        *(ushort4*)(op + j) = u0;
        *(ushort4*)(op + j + 4) = u1;
    }
    float sq = (q == 0) ? s0 : (q == 1) ? s1 : (q == 2) ? s2 : s3;
    int s = src[e], d = dst[e];
    float u = vs[s * 4 + q] + vd[d * 4 + q] + sq;
    u = u > 0.f ? u : ALPHA_ * u;
    w4p[(size_t)pe * 4 + q] = __expf(-u);
}

// ---------------- layer-1 node aggregation: streaming reads -------
// accU[n][1152] bf16: per head k: [k*256..+127]=(Sum w_k*ee)/(rs_k+eps),
//                                  [k*256+128..+255]=(Sum w_k*h[d])/(rs_k+eps);
//                     [1024..1151]=h[n]*flag
__global__ __launch_bounds__(256) void node_l1(const float* __restrict__ ent,
        const unsigned short* __restrict__ eembp, const float* __restrict__ w4p,
        const int* __restrict__ dord, const int* __restrict__ rowptr,
        unsigned short* __restrict__ accU) {
    int tid = threadIdx.x;
    int l = tid & 63, wv = tid >> 6;
    int n = blockIdx.x * 4 + wv;
    int p0 = rowptr[n], p1 = rowptr[n + 1];
    float aEx[4] = {}, aEy[4] = {}, aHx[4] = {}, aHy[4] = {}, r[4] = {};
    float2 ee_n = make_float2(0.f, 0.f), hd_n = make_float2(0.f, 0.f);
    float4 w_n = make_float4(0.f, 0.f, 0.f, 0.f);
    if (p0 < p1) {
        unsigned int ue = *(const unsigned int*)(eembp + (size_t)p0 * 128 + 2 * l);
        ee_n = make_float2(bf2f((unsigned short)ue), bf2f((unsigned short)(ue >> 16)));
        hd_n = *(const float2*)(ent + (size_t)dord[p0] * 128 + 2 * l);
        w_n  = *(const float4*)(w4p + (size_t)p0 * 4);
    }
    for (int p = p0; p < p1; ++p) {
        float2 ee = ee_n, hd = hd_n;
        float4 w = w_n;
        if (p + 1 < p1) {
            unsigned int ue = *(const unsigned int*)(eembp + (size_t)(p + 1) * 128 + 2 * l);
            ee_n = make_float2(bf2f((unsigned short)ue), bf2f((unsigned short)(ue >> 16)));
            hd_n = *(const float2*)(ent + (size_t)dord[p + 1] * 128 + 2 * l);
            w_n  = *(const float4*)(w4p + (size_t)(p + 1) * 4);
        }
        r[0] += w.x; r[1] += w.y; r[2] += w.z; r[3] += w.w;
        aEx[0] = fmaf(w.x, ee.x, aEx[0]); aEy[0] = fmaf(w.x, ee.y, aEy[0]);
        aEx[1] = fmaf(w.y, ee.x, aEx[1]); aEy[1] = fmaf(w.y, ee.y, aEy[1]);
        aEx[2] = fmaf(w.z, ee.x, aEx[2]); aEy[2] = fmaf(w.z, ee.y, aEy[2]);
        aEx[3] = fmaf(w.w, ee.x, aEx[3]); aEy[3] = fmaf(w.w, ee.y, aEy[3]);
        aHx[0] = fmaf(w.x, hd.x, aHx[0]); aHy[0] = fmaf(w.x, hd.y, aHy[0]);
        aHx[1] = fmaf(w.y, hd.x, aHx[1]); aHy[1] = fmaf(w.y, hd.y, aHy[1]);
        aHx[2] = fmaf(w.z, hd.x, aHx[2]); aHy[2] = fmaf(w.z, hd.y, aHy[2]);
        aHx[3] = fmaf(w.w, hd.x, aHx[3]); aHy[3] = fmaf(w.w, hd.y, aHy[3]);
    }
    unsigned short* ub = accU + (size_t)n * 1152;
#pragma unroll
    for (int k = 0; k < 4; ++k) {
        float inv = 1.f / (r[k] + 1e-16f);
        *(unsigned int*)(ub + k * 256 + 2 * l) =
            (unsigned)f2bf(aEx[k] * inv) | ((unsigned)f2bf(aEy[k] * inv) << 16);
        *(unsigned int*)(ub + k * 256 + 128 + 2 * l) =
            (unsigned)f2bf(aHx[k] * inv) | ((unsigned)f2bf(aHy[k] * inv) << 16);
    }
    float flag = (p1 > p0) ? 1.f : 0.f;
    float2 hn = *(const float2*)(ent + (size_t)n * 128 + 2 * l);
    *(unsigned int*)(ub + 1024 + 2 * l) =
        (unsigned)f2bf(hn.x * flag) | ((unsigned)f2bf(hn.y * flag) << 16);
}

// ---------------- projx: 2-phase dbuf; x[n][z*64+c] = elu(accU @ BX^T) ------
__global__ __launch_bounds__(256) void projx(const unsigned short* __restrict__ accU,
        const unsigned short* __restrict__ BX, unsigned short* __restrict__ xb) {
    __shared__ unsigned short Ab[2][128 * PADK];
    __shared__ unsigned short Bb[2][64 * PADK];
    int tid = threadIdx.x, lane = tid & 63, wv = tid >> 6;
    int z = blockIdx.x;
    int bm = blockIdx.y * 128;
    int r16 = lane & 15, g = lane >> 4;
    f32x4 acc[2][4] = {};
    ushort4 ra[4], rb[2];

#define PX_LOADA(k0) { \
        int aoff = ((k0) < 256) ? z * 256 + (k0) : 1024 + ((k0) - 256); \
        _Pragma("unroll") \
        for (int i = 0; i < 4; ++i) { \
            int e = i * 1024 + tid * 4; \
            int rr = e >> 5, kk = e & 31; \
            int gr = bm + rr; \
            ra[i] = (gr < N_NODES) ? *(const ushort4*)(accU + (size_t)gr * 1152 + aoff + kk) \
                                   : make_ushort4(0, 0, 0, 0); \
        } \
        { int e = tid * 8; int rr = e >> 5, kk = e & 31; \
          const unsigned short* bp = BX + (size_t)(z * 64 + rr) * 384 + (k0) + kk; \
          rb[0] = *(const ushort4*)bp; rb[1] = *(const ushort4*)(bp + 4); } }

#define PX_WRITE(buf) { \
        _Pragma("unroll") \
        for (int i = 0; i < 4; ++i) { \
            int e = i * 1024 + tid * 4; \
            int rr = e >> 5, kk = e & 31; \
            *(ushort4*)&Ab[buf][rr * PADK + kk] = ra[i]; \
        } \
        { int e = tid * 8; int rr = e >> 5, kk = e & 31; \
          *(ushort4*)&Bb[buf][rr * PADK + kk] = rb[0]; \
          *(ushort4*)&Bb[buf][rr * PADK + kk + 4] = rb[1]; } }

    PX_LOADA(0)
    PX_WRITE(0)
    __syncthreads();
    int cur = 0;
    for (int kt = 0; kt < 12; ++kt) {
        if (kt + 1 < 12) PX_LOADA((kt + 1) * BK)
        bf16x8 af[2], bfv[4];
#pragma unroll
        for (int m = 0; m < 2; ++m)
            af[m] = *(const bf16x8*)&Ab[cur][(wv * 32 + m * 16 + r16) * PADK + g * 8];
#pragma unroll
        for (int nn = 0; nn < 4; ++nn)
            bfv[nn] = *(const bf16x8*)&Bb[cur][(nn * 16 + r16) * PADK + g * 8];
#pragma unroll
        for (int m = 0; m < 2; ++m)
#pragma unroll
            for (int nn = 0; nn < 4; ++nn)
                acc[m][nn] = __builtin_amdgcn_mfma_f32_16x16x32_bf16(af[m], bfv[nn], acc[m][nn], 0, 0, 0);
        if (kt + 1 < 12) PX_WRITE(cur ^ 1)
        __syncthreads();
        cur ^= 1;
    }
#pragma unroll
    for (int m = 0; m < 2; ++m)
#pragma unroll
        for (int j = 0; j < 4; ++j) {
            int gr = bm + wv * 32 + m * 16 + g * 4 + j;
            if (gr >= N_NODES) continue;
#pragma unroll
            for (int nn = 0; nn < 4; ++nn)
                xb[(size_t)gr * 256 + z * 64 + nn * 16 + r16] = f2bf(elu_(acc[m][nn][j]));
        }
#undef PX_LOADA
#undef PX_WRITE
}

// ---------------- layer-2 score scalars ----------------
__global__ __launch_bounds__(256) void vsd2(const unsigned short* __restrict__ xb,
        const float* __restrict__ csd, float* __restrict__ vs2, float* __restrict__ vd2) {
    __shared__ float cs[512];
    int tid = threadIdx.x;
    for (int i = tid; i < 512; i += 256) cs[i] = csd[i];
    __syncthreads();
    int l = tid & 63, wv = tid >> 6;
    int n = blockIdx.x * 4 + wv;
    ushort4 u = *(const ushort4*)(xb + (size_t)n * 256 + 4 * l);
    float x0 = bf2f(u.x), x1 = bf2f(u.y), x2 = bf2f(u.z), x3 = bf2f(u.w);
    float ps = x0 * cs[4 * l] + x1 * cs[4 * l + 1] + x2 * cs[4 * l + 2] + x3 * cs[4 * l + 3];
    float pd = x0 * cs[256 + 4 * l] + x1 * cs[256 + 4 * l + 1] + x2 * cs[256 + 4 * l + 2] + x3 * cs[256 + 4 * l + 3];
#pragma unroll
    for (int off = 32; off; off >>= 1) { ps += __shfl_xor(ps, off); pd += __shfl_xor(pd, off); }
    if (l == 0) { vs2[n] = ps; vd2[n] = pd; }
}

// ---------------- layer-2 node aggregation: 2 waves/node ----------------
__global__ __launch_bounds__(256) void node_l2(const unsigned short* __restrict__ xb,
        const float* __restrict__ rel2t, const int* __restrict__ dord,
        const int* __restrict__ tord, const int* __restrict__ rowptr,
        const float* __restrict__ vs2, const float* __restrict__ vd2,
        const float* __restrict__ st2, unsigned short* __restrict__ accV,
        unsigned short* __restrict__ accRn) {
    __shared__ float comb[2][9][65];
    int tid = threadIdx.x, l = tid & 63, wv = tid >> 6;
    int slot = wv >> 1, h = wv & 1;
    int n = blockIdx.x * 2 + slot;
    int p0 = rowptr[n], p1 = rowptr[n + 1];
    float s0 = vs2[n];
    float aX[4] = {}, aR[4] = {};
    float rs = 0.f;
    ushort4 xv_n = make_ushort4(0, 0, 0, 0);
    float4 rt_n = make_float4(0.f, 0.f, 0.f, 0.f);
    float vdn_ = 0.f, stn_ = 0.f;
    int p = p0 + h;
    if (p < p1) {
        int d = dord[p], t = tord[p];
        xv_n = *(const ushort4*)(xb + (size_t)d * 256 + 4 * l);
        rt_n = *(const float4*)(rel2t + (size_t)t * 256 + 4 * l);
        vdn_ = vd2[d]; stn_ = st2[t];
    }
    for (; p < p1; p += 2) {
        ushort4 xv = xv_n; float4 rt = rt_n;
        float vdv = vdn_, stv = stn_;
        if (p + 2 < p1) {
            int d = dord[p + 2], t = tord[p + 2];
            xv_n = *(const ushort4*)(xb + (size_t)d * 256 + 4 * l);
            rt_n = *(const float4*)(rel2t + (size_t)t * 256 + 4 * l);
            vdn_ = vd2[d]; stn_ = st2[t];
        }
        float s = s0 + vdv + stv;
        s = s > 0.f ? s : ALPHA_ * s;
        float wgt = __expf(-s);
        rs += wgt;
        aX[0] = fmaf(wgt, bf2f(xv.x), aX[0]);
        aX[1] = fmaf(wgt, bf2f(xv.y), aX[1]);
        aX[2] = fmaf(wgt, bf2f(xv.z), aX[2]);
        aX[3] = fmaf(wgt, bf2f(xv.w), aX[3]);
        aR[0] = fmaf(wgt, rt.x, aR[0]);
        aR[1] = fmaf(wgt, rt.y, aR[1]);
        aR[2] = fmaf(wgt, rt.z, aR[2]);
        aR[3] = fmaf(wgt, rt.w, aR[3]);
    }
    float* cb = &comb[slot][0][l];
    if (h) {
#pragma unroll
        for (int k = 0; k < 4; ++k) {
            cb[k * 65] = aX[k];
            cb[(4 + k) * 65] = aR[k];
        }
        cb[8 * 65] = rs;
    }
    __syncthreads();
    if (!h) {
#pragma unroll
        for (int k = 0; k < 4; ++k) {
            aX[k] += cb[k * 65];
            aR[k] += cb[(4 + k) * 65];
        }
        rs += cb[8 * 65];
        float inv = 1.f / (rs + 1e-16f);
        unsigned short* vb = accV + (size_t)n * 512;
        ushort4 o;
        o.x = f2bf(aX[0] * inv); o.y = f2bf(aX[1] * inv);
        o.z = f2bf(aX[2] * inv); o.w = f2bf(aX[3] * inv);
        *(ushort4*)(vb + 4 * l) = o;
        ushort4 xn = *(const ushort4*)(xb + (size_t)n * 256 + 4 * l);
        if (p0 == p1) xn = make_ushort4(0, 0, 0, 0);
        *(ushort4*)(vb + 256 + 4 * l) = xn;
        ushort4 rn;
        rn.x = f2bf(aR[0] * inv); rn.y = f2bf(aR[1] * inv);
        rn.z = f2bf(aR[2] * inv); rn.w = f2bf(aR[3] * inv);
        *(ushort4*)(accRn + (size_t)n * 256 + 4 * l) = rn;
    }
}

// ---------------- final2: 2-phase dbuf; out = elu(accV @ B2^T + accRn) --------
__global__ __launch_bounds__(256) void final2(const unsigned short* __restrict__ accV,
        const unsigned short* __restrict__ B2, const unsigned short* __restrict__ accRn,
        float* __restrict__ out) {
    __shared__ unsigned short Ab[2][128 * PADK];
    __shared__ unsigned short Bb[2][128 * PADK];
    int tid = threadIdx.x, lane = tid & 63, wv = tid >> 6;
    int wr = wv >> 1, wc = wv & 1;
    int bm = blockIdx.y * 128, bn = blockIdx.x * 128;
    int r16 = lane & 15, g = lane >> 4;
    f32x4 acc[4][4] = {};
    ushort4 ra[4], rb[4];

#define F2_LOAD(k0) { \
        _Pragma("unroll") \
        for (int i = 0; i < 4; ++i) { \
            int e = i * 1024 + tid * 4; \
            int rr = e >> 5, kk = e & 31; \
            int gr = bm + rr; \
            ra[i] = (gr < N_NODES) ? *(const ushort4*)(accV + (size_t)gr * 512 + (k0) + kk) \
                                   : make_ushort4(0, 0, 0, 0); \
            rb[i] = *(const ushort4*)(B2 + (size_t)(bn + rr) * 512 + (k0) + kk); \
        } }

#define F2_WRITE(buf) { \
        _Pragma("unroll") \
        for (int i = 0; i < 4; ++i) { \
            int e = i * 1024 + tid * 4; \
            int rr = e >> 5, kk = e & 31; \
            *(ushort4*)&Ab[buf][rr * PADK + kk] = ra[i]; \
            *(ushort4*)&Bb[buf][rr * PADK + kk] = rb[i]; \
        } }

    F2_LOAD(0)
    F2_WRITE(0)
    __syncthreads();
    int cur = 0;
    for (int kt = 0; kt < 16; ++kt) {
        if (kt + 1 < 16) F2_LOAD((kt + 1) * BK)
        bf16x8 afrag[4], bfrag[4];
#pragma unroll
        for (int m = 0; m < 4; ++m)
            afrag[m] = *(const bf16x8*)&Ab[cur][(wr * 64 + m * 16 + r16) * PADK + g * 8];
#pragma unroll
        for (int nn = 0; nn < 4; ++nn)
            bfrag[nn] = *(const bf16x8*)&Bb[cur][(wc * 64 + nn * 16 + r16) * PADK + g * 8];
#pragma unroll
        for (int m = 0; m < 4; ++m)
#pragma unroll
            for (int nn = 0; nn < 4; ++nn)
                acc[m][nn] = __builtin_amdgcn_mfma_f32_16x16x32_bf16(afrag[m], bfrag[nn], acc[m][nn], 0, 0, 0);
        if (kt + 1 < 16) F2_WRITE(cur ^ 1)
        __syncthreads();
        cur ^= 1;
    }
#pragma unroll
    for (int m = 0; m < 4; ++m)
#pragma unroll
        for (int j = 0; j < 4; ++j) {
            int gr = bm + wr * 64 + m * 16 + g * 4 + j;
            if (gr >= N_NODES) continue;
#pragma unroll
            for (int nn = 0; nn < 4; ++nn) {
                int gc = bn + wc * 64 + nn * 16 + r16;
                out[(size_t)gr * 256 + gc] = elu_(acc[m][nn][j] + bf2f(accRn[(size_t)gr * 256 + gc]));
            }
        }
#undef F2_LOAD
#undef F2_WRITE
}

extern "C" void kernel_launch(void* const* d_in, const int* in_sizes, int n_in,
                              void* d_out, int out_size, void* d_ws, size_t ws_size,
                              hipStream_t stream) {
    const float* entity    = (const float*)d_in[0];
    const float* relemb    = (const float*)d_in[1];
    const float* edge_emb  = (const float*)d_in[2];
    const float* a_heads   = (const float*)d_in[3];
    const float* a2h       = (const float*)d_in[4];
    const float* a_out     = (const float*)d_in[5];
    const float* a2o       = (const float*)d_in[6];
    const float* W_1       = (const float*)d_in[7];
    const int*   elist     = (const int*)d_in[8];
    const int*   etype     = (const int*)d_in[9];
    const int*   src = elist;
    const int*   dst = elist + N_EDGES;
    float* out = (float*)d_out;

    char* ws = (char*)d_ws;
    size_t off = 0;
    auto alloc = [&](size_t bytes) -> void* {
        void* p = ws + off;
        off += (bytes + 255) & ~(size_t)255;
        return p;
    };
    float* rel2t   = (float*)alloc((size_t)N_REL * DIM2 * 4);
    float* cvec    = (float*)alloc(1536 * 4);
    float* csd     = (float*)alloc(512 * 4);
    float* st2     = (float*)alloc(N_REL * 4);
    float* vs      = (float*)alloc((size_t)N_NODES * 4 * 4);
    float* vd      = (float*)alloc((size_t)N_NODES * 4 * 4);
    float* vs2     = (float*)alloc((size_t)N_NODES * 4);
    float* vd2     = (float*)alloc((size_t)N_NODES * 4);
    float* w4p     = (float*)alloc((size_t)N_EDGES * 4 * 4);
    int*   deg     = (int*)alloc((size_t)N_NODES * 4);
    int*   rowptr  = (int*)alloc((size_t)(N_NODES + 1) * 4);
    int*   cur     = (int*)alloc((size_t)N_NODES * 4);
    int*   bsum    = (int*)alloc(128 * 4);
    int*   pos     = (int*)alloc((size_t)N_EDGES * 4);
    int*   dord    = (int*)alloc((size_t)N_EDGES * 4);
    int*   tord    = (int*)alloc((size_t)N_EDGES * 4);
    unsigned short* accU = (unsigned short*)alloc((size_t)N_NODES * 1152 * 2);
    unsigned short* B2   = (unsigned short*)alloc(256 * 512 * 2);
    unsigned short* BX   = (unsigned short*)alloc(256 * 384 * 2);
    // aliased region: eembp (E*128 bf16 = 102.4MB) lives until node_l1 completes;
    // xb / accV / accRn (25.6+51.2+25.6 = 102.4MB) are written only after.
    char* region = (char*)alloc((size_t)N_EDGES * 128 * 2);
    unsigned short* eembp = (unsigned short*)region;
    unsigned short* xb    = (unsigned short*)region;
    unsigned short* accV  = (unsigned short*)(region + (size_t)N_NODES * 256 * 2);
    unsigned short* accRn = (unsigned short*)(region + (size_t)N_NODES * 256 * 2 + (size_t)N_NODES * 512 * 2);
    (void)ws_size; (void)in_sizes; (void)n_in; (void)out_size;

    // ---- weights / tables ----
    prep_all<<<512, 256, 0, stream>>>(a_heads, a_out, a2h, a2o, B2, BX, cvec, csd);
    rel2fused<<<N_REL, 256, 0, stream>>>(relemb, W_1, a_out, a2o, rel2t, st2);

    // ---- CSR build ----
    hipMemsetAsync(deg, 0, (size_t)N_NODES * 4, stream);
    histk<<<(N_EDGES + 255) / 256, 256, 0, stream>>>(src, deg);
    scan_part<<<NB_SCAN, 512, 0, stream>>>(deg, rowptr, bsum);
    scan_tops<<<1, 64, 0, stream>>>(bsum);
    scan_add<<<(N_NODES + 255) / 256, 256, 0, stream>>>(rowptr, bsum, cur);
    scatterk<<<(N_EDGES + 255) / 256, 256, 0, stream>>>(src, dst, etype, cur, pos, dord, tord);

    // ---- layer 1 ----
    gemv1<<<N_NODES / 4, 256, 0, stream>>>(entity, cvec, vs, vd);
    edge_w<<<(N_EDGES + 63) / 64, 256, 0, stream>>>(edge_emb, src, dst, pos, vs, vd, cvec, w4p, eembp);
    node_l1<<<N_NODES / 4, 256, 0, stream>>>(entity, eembp, w4p, dord, rowptr, accU);
    projx<<<dim3(4, (N_NODES + 127) / 128), 256, 0, stream>>>(accU, BX, xb);

    // ---- layer 2 ----
    vsd2<<<N_NODES / 4, 256, 0, stream>>>(xb, csd, vs2, vd2);
    node_l2<<<N_NODES / 2, 256, 0, stream>>>(xb, rel2t, dord, tord, rowptr,
                                             vs2, vd2, st2, accV, accRn);
    final2<<<dim3(2, (N_NODES + 127) / 128), 256, 0, stream>>>(accV, B2, accRn, out);
}

// Round 12
// 497.748 us; speedup vs baseline: 1.0494x; 1.0494x over previous
//
#include <hip/hip_runtime.h>
#include <hip/hip_bf16.h>

#define N_NODES 50000
#define N_EDGES 400000
#define NFEAT 128
#define N_REL 500
#define DIM2 256
#define ALPHA_ 0.2f
#define NB_SCAN 98          // ceil(50000/512)
#define BK 32
#define PADK 40

typedef __attribute__((ext_vector_type(4))) float f32x4;
typedef __attribute__((ext_vector_type(8))) short bf16x8;

__device__ __forceinline__ unsigned short f2bf(float x) {
    union { float f; unsigned int u; } v; v.f = x;
    unsigned int r = v.u + 0x7FFFu + ((v.u >> 16) & 1u);
    return (unsigned short)(r >> 16);
}
__device__ __forceinline__ float bf2f(unsigned short u) {
    union { float f; unsigned int i; } v; v.i = (unsigned int)u << 16; return v.f;
}
__device__ __forceinline__ float elu_(float v) { return v > 0.f ? v : expm1f(v); }

// ---------------- fused weight prep ----------------
__global__ void prep_all(const float* __restrict__ a_heads, const float* __restrict__ a_out,
                         const float* __restrict__ a2h, const float* __restrict__ a2o,
                         unsigned short* __restrict__ B2, unsigned short* __restrict__ BX,
                         float* __restrict__ cvec, float* __restrict__ csd) {
    int idx = blockIdx.x * 256 + threadIdx.x;   // 512 blocks x 256
    if (idx < 256 * 512) {
        int n = idx >> 9, k = idx & 511;
        float v = (k < 256) ? a_out[(size_t)n * 768 + 256 + k]
                            : a_out[(size_t)n * 768 + (k - 256)];
        B2[idx] = f2bf(v);
    }
    if (idx < 256 * 384) {
        int c = idx / 384, k = idx % 384;
        int perm = (k < 128) ? 256 + k : (k < 256) ? k : k - 256;
        BX[idx] = f2bf(a_heads[(size_t)c * 384 + perm]);
    }
    if (idx < 512) {
        int k = idx >> 7, j = idx & 127;
        float s1 = 0.f, s2 = 0.f, s3 = 0.f;
        for (int c = 0; c < 64; ++c) {
            float a2 = a2h[k * 64 + c];
            const float* base = a_heads + (size_t)(k * 64 + c) * 384;
            s1 = fmaf(base[j], a2, s1);
            s2 = fmaf(base[128 + j], a2, s2);
            s3 = fmaf(base[256 + j], a2, s3);
        }
        cvec[idx] = s1; cvec[512 + idx] = s2; cvec[1024 + idx] = s3;
    } else if (idx < 1024) {
        int j = idx - 512;
        float s = 0.f, d = 0.f;
        for (int c = 0; c < 256; ++c) {
            float a = a2o[c];
            s = fmaf(a_out[(size_t)c * 768 + j], a, s);
            d = fmaf(a_out[(size_t)c * 768 + 256 + j], a, d);
        }
        csd[j] = s; csd[256 + j] = d;
    }
}

// ---------------- fused relation table: rel2t + st2 ----------------
__global__ __launch_bounds__(256) void rel2fused(const float* __restrict__ relemb,
        const float* __restrict__ W_1, const float* __restrict__ a_out,
        const float* __restrict__ a2o, float* __restrict__ rel2t,
        float* __restrict__ st2) {
    __shared__ float orow[256];
    __shared__ float ws[4];
    int r = blockIdx.x, c = threadIdx.x;
    float s = 0.f;
    const float* re = relemb + (size_t)r * 128;
    for (int k = 0; k < 128; ++k) s = fmaf(re[k], W_1[(size_t)k * 256 + c], s);
    orow[c] = s;
    __syncthreads();
    float t = 0.f;
    const float* ao = a_out + (size_t)c * 768 + 512;
    for (int k = 0; k < 256; ++k) t = fmaf(orow[k], ao[k], t);
    rel2t[(size_t)r * 256 + c] = t;
    float p = t * a2o[c];
#pragma unroll
    for (int off = 32; off; off >>= 1) p += __shfl_xor(p, off);
    if ((c & 63) == 0) ws[c >> 6] = p;
    __syncthreads();
    if (c == 0) st2[r] = ws[0] + ws[1] + ws[2] + ws[3];
}

// ---------------- CSR build ----------------
__global__ void histk(const int* __restrict__ src, int* __restrict__ deg) {
    int e = blockIdx.x * 256 + threadIdx.x;
    if (e < N_EDGES) atomicAdd(&deg[src[e]], 1);
}

__global__ void scan_part(const int* __restrict__ deg, int* __restrict__ rowptr,
                          int* __restrict__ bsum) {
    __shared__ int buf[512];
    int t = threadIdx.x, b = blockIdx.x;
    int i = b * 512 + t;
    int v = (i < N_NODES) ? deg[i] : 0;
    buf[t] = v;
    __syncthreads();
    for (int off = 1; off < 512; off <<= 1) {
        int x = buf[t];
        int y = (t >= off) ? buf[t - off] : 0;
        __syncthreads();
        buf[t] = x + y;
        __syncthreads();
    }
    if (i < N_NODES) rowptr[i] = buf[t] - v;
    if (t == 511) bsum[b] = buf[511];
}

__global__ void scan_tops(int* __restrict__ bsum) {
    if (threadIdx.x == 0) {
        int run = 0;
        for (int b = 0; b < NB_SCAN; ++b) { int v = bsum[b]; bsum[b] = run; run += v; }
    }
}

__global__ void scan_add(int* __restrict__ rowptr, const int* __restrict__ bsum,
                         int* __restrict__ cur) {
    int i = blockIdx.x * 256 + threadIdx.x;
    if (i == 0) rowptr[N_NODES] = N_EDGES;
    if (i < N_NODES) {
        int r = rowptr[i] + bsum[i >> 9];
        rowptr[i] = r;
        cur[i] = r;
    }
}

// records order[p]=e and pos[e]=p
__global__ void scatterk(const int* __restrict__ src, const int* __restrict__ dst,
                         const int* __restrict__ etype, int* __restrict__ cur,
                         int* __restrict__ order, int* __restrict__ pos,
                         int* __restrict__ dord, int* __restrict__ tord) {
    int e = blockIdx.x * 256 + threadIdx.x;
    if (e < N_EDGES) {
        int p = atomicAdd(&cur[src[e]], 1);
        order[p] = e;
        pos[e] = p;
        dord[p] = dst[e];
        tord[p] = etype[e];
    }
}

// ---------------- per-node score scalars, layer 1 ----------------
__global__ __launch_bounds__(256) void gemv1(const float* __restrict__ ent,
                                             const float* __restrict__ cvec,
                                             float* __restrict__ vs, float* __restrict__ vd) {
    __shared__ float sv[1024];
    int tid = threadIdx.x;
    for (int i = tid; i < 1024; i += 256) sv[i] = cvec[i];
    __syncthreads();
    int l = tid & 63, wv = tid >> 6;
    int n = blockIdx.x * 4 + wv;
    float2 e = *(const float2*)(ent + (size_t)n * 128 + 2 * l);
    float ps0 = e.x * sv[2 * l] + e.y * sv[2 * l + 1];
    float ps1 = e.x * sv[128 + 2 * l] + e.y * sv[128 + 2 * l + 1];
    float ps2 = e.x * sv[256 + 2 * l] + e.y * sv[256 + 2 * l + 1];
    float ps3 = e.x * sv[384 + 2 * l] + e.y * sv[384 + 2 * l + 1];
    float pd0 = e.x * sv[512 + 2 * l] + e.y * sv[512 + 2 * l + 1];
    float pd1 = e.x * sv[640 + 2 * l] + e.y * sv[640 + 2 * l + 1];
    float pd2 = e.x * sv[768 + 2 * l] + e.y * sv[768 + 2 * l + 1];
    float pd3 = e.x * sv[896 + 2 * l] + e.y * sv[896 + 2 * l + 1];
#pragma unroll
    for (int off = 32; off; off >>= 1) {
        ps0 += __shfl_xor(ps0, off); ps1 += __shfl_xor(ps1, off);
        ps2 += __shfl_xor(ps2, off); ps3 += __shfl_xor(ps3, off);
        pd0 += __shfl_xor(pd0, off); pd1 += __shfl_xor(pd1, off);
        pd2 += __shfl_xor(pd2, off); pd3 += __shfl_xor(pd3, off);
    }
    if (l == 0) {
        vs[n * 4 + 0] = ps0; vs[n * 4 + 1] = ps1; vs[n * 4 + 2] = ps2; vs[n * 4 + 3] = ps3;
        vd[n * 4 + 0] = pd0; vd[n * 4 + 1] = pd1; vd[n * 4 + 2] = pd2; vd[n * 4 + 3] = pd3;
    }
}

// ---------------- edge weights: 4 lanes/edge, conflict-free LDS, w4p CSR-ordered --
// crsp layout: [h*144 + q*36 + j]  (q-starts hit banks 0/4/8/12 -> no conflict)
__global__ __launch_bounds__(256) void edge_w(const float* __restrict__ eemb,
        const int* __restrict__ src, const int* __restrict__ dst,
        const int* __restrict__ pos, const float* __restrict__ vs,
        const float* __restrict__ vd, const float* __restrict__ cvec,
        float* __restrict__ w4p) {
    __shared__ float crsp[576];
    int t = threadIdx.x;
    for (int i = t; i < 576; i += 256) {
        int h = i / 144, rem = i % 144;
        int q = rem / 36, j = rem % 36;
        crsp[i] = (j < 32) ? cvec[1024 + h * 128 + q * 32 + j] : 0.f;
    }
    __syncthreads();
    int q = t & 3;
    int e = blockIdx.x * 64 + (t >> 2);
    if (e >= N_EDGES) return;
    const float* ep = eemb + (size_t)e * 128 + q * 32;
    const float* c0p = &crsp[q * 36];
    float s0 = 0.f, s1 = 0.f, s2 = 0.f, s3 = 0.f;
    for (int j = 0; j < 32; j += 4) {
        float4 v  = *(const float4*)(ep + j);
        float4 c0 = *(const float4*)(c0p + j);
        float4 c1 = *(const float4*)(c0p + 144 + j);
        float4 c2 = *(const float4*)(c0p + 288 + j);
        float4 c3 = *(const float4*)(c0p + 432 + j);
        s0 = fmaf(v.x, c0.x, s0); s0 = fmaf(v.y, c0.y, s0);
        s0 = fmaf(v.z, c0.z, s0); s0 = fmaf(v.w, c0.w, s0);
        s1 = fmaf(v.x, c1.x, s1); s1 = fmaf(v.y, c1.y, s1);
        s1 = fmaf(v.z, c1.z, s1); s1 = fmaf(v.w, c1.w, s1);
        s2 = fmaf(v.x, c2.x, s2); s2 = fmaf(v.y, c2.y, s2);
        s2 = fmaf(v.z, c2.z, s2); s2 = fmaf(v.w, c2.w, s2);
        s3 = fmaf(v.x, c3.x, s3); s3 = fmaf(v.y, c3.y, s3);
        s3 = fmaf(v.z, c3.z, s3); s3 = fmaf(v.w, c3.w, s3);
    }
    s0 += __shfl_xor(s0, 1); s0 += __shfl_xor(s0, 2);
    s1 += __shfl_xor(s1, 1); s1 += __shfl_xor(s1, 2);
    s2 += __shfl_xor(s2, 1); s2 += __shfl_xor(s2, 2);
    s3 += __shfl_xor(s3, 1); s3 += __shfl_xor(s3, 2);
    float sq = (q == 0) ? s0 : (q == 1) ? s1 : (q == 2) ? s2 : s3;
    int s = src[e], d = dst[e];
    float u = vs[s * 4 + q] + vd[d * 4 + q] + sq;
    u = u > 0.f ? u : ALPHA_ * u;
    w4p[(size_t)pos[e] * 4 + q] = __expf(-u);
}

// ---------------- layer-1 node aggregation: order-gather ee, sequential w4p -------
__global__ __launch_bounds__(256) void node_l1(const float* __restrict__ ent,
        const float* __restrict__ eemb, const float* __restrict__ w4p,
        const int* __restrict__ order, const int* __restrict__ dord,
        const int* __restrict__ rowptr, unsigned short* __restrict__ accU) {
    int tid = threadIdx.x;
    int l = tid & 63, wv = tid >> 6;
    int n = blockIdx.x * 4 + wv;
    int p0 = rowptr[n], p1 = rowptr[n + 1];
    float aEx[4] = {}, aEy[4] = {}, aHx[4] = {}, aHy[4] = {}, r[4] = {};
    float2 ee_n = make_float2(0.f, 0.f), hd_n = make_float2(0.f, 0.f);
    float4 w_n = make_float4(0.f, 0.f, 0.f, 0.f);
    if (p0 < p1) {
        ee_n = *(const float2*)(eemb + (size_t)order[p0] * 128 + 2 * l);
        hd_n = *(const float2*)(ent + (size_t)dord[p0] * 128 + 2 * l);
        w_n  = *(const float4*)(w4p + (size_t)p0 * 4);
    }
    for (int p = p0; p < p1; ++p) {
        float2 ee = ee_n, hd = hd_n;
        float4 w = w_n;
        if (p + 1 < p1) {
            ee_n = *(const float2*)(eemb + (size_t)order[p + 1] * 128 + 2 * l);
            hd_n = *(const float2*)(ent + (size_t)dord[p + 1] * 128 + 2 * l);
            w_n  = *(const float4*)(w4p + (size_t)(p + 1) * 4);
        }
        r[0] += w.x; r[1] += w.y; r[2] += w.z; r[3] += w.w;
        aEx[0] = fmaf(w.x, ee.x, aEx[0]); aEy[0] = fmaf(w.x, ee.y, aEy[0]);
        aEx[1] = fmaf(w.y, ee.x, aEx[1]); aEy[1] = fmaf(w.y, ee.y, aEy[1]);
        aEx[2] = fmaf(w.z, ee.x, aEx[2]); aEy[2] = fmaf(w.z, ee.y, aEy[2]);
        aEx[3] = fmaf(w.w, ee.x, aEx[3]); aEy[3] = fmaf(w.w, ee.y, aEy[3]);
        aHx[0] = fmaf(w.x, hd.x, aHx[0]); aHy[0] = fmaf(w.x, hd.y, aHy[0]);
        aHx[1] = fmaf(w.y, hd.x, aHx[1]); aHy[1] = fmaf(w.y, hd.y, aHy[1]);
        aHx[2] = fmaf(w.z, hd.x, aHx[2]); aHy[2] = fmaf(w.z, hd.y, aHy[2]);
        aHx[3] = fmaf(w.w, hd.x, aHx[3]); aHy[3] = fmaf(w.w, hd.y, aHy[3]);
    }
    unsigned short* ub = accU + (size_t)n * 1152;
#pragma unroll
    for (int k = 0; k < 4; ++k) {
        float inv = 1.f / (r[k] + 1e-16f);
        *(unsigned int*)(ub + k * 256 + 2 * l) =
            (unsigned)f2bf(aEx[k] * inv) | ((unsigned)f2bf(aEy[k] * inv) << 16);
        *(unsigned int*)(ub + k * 256 + 128 + 2 * l) =
            (unsigned)f2bf(aHx[k] * inv) | ((unsigned)f2bf(aHy[k] * inv) << 16);
    }
    float flag = (p1 > p0) ? 1.f : 0.f;
    float2 hn = *(const float2*)(ent + (size_t)n * 128 + 2 * l);
    *(unsigned int*)(ub + 1024 + 2 * l) =
        (unsigned)f2bf(hn.x * flag) | ((unsigned)f2bf(hn.y * flag) << 16);
}

// ---------------- projx: 2-phase dbuf; x[n][z*64+c] = elu(accU @ BX^T) ------
__global__ __launch_bounds__(256) void projx(const unsigned short* __restrict__ accU,
        const unsigned short* __restrict__ BX, unsigned short* __restrict__ xb) {
    __shared__ unsigned short Ab[2][128 * PADK];
    __shared__ unsigned short Bb[2][64 * PADK];
    int tid = threadIdx.x, lane = tid & 63, wv = tid >> 6;
    int z = blockIdx.x;
    int bm = blockIdx.y * 128;
    int r16 = lane & 15, g = lane >> 4;
    f32x4 acc[2][4] = {};
    ushort4 ra[4], rb[2];

#define PX_LOADA(k0) { \
        int aoff = ((k0) < 256) ? z * 256 + (k0) : 1024 + ((k0) - 256); \
        _Pragma("unroll") \
        for (int i = 0; i < 4; ++i) { \
            int e = i * 1024 + tid * 4; \
            int rr = e >> 5, kk = e & 31; \
            int gr = bm + rr; \
            ra[i] = (gr < N_NODES) ? *(const ushort4*)(accU + (size_t)gr * 1152 + aoff + kk) \
                                   : make_ushort4(0, 0, 0, 0); \
        } \
        { int e = tid * 8; int rr = e >> 5, kk = e & 31; \
          const unsigned short* bp = BX + (size_t)(z * 64 + rr) * 384 + (k0) + kk; \
          rb[0] = *(const ushort4*)bp; rb[1] = *(const ushort4*)(bp + 4); } }

#define PX_WRITE(buf) { \
        _Pragma("unroll") \
        for (int i = 0; i < 4; ++i) { \
            int e = i * 1024 + tid * 4; \
            int rr = e >> 5, kk = e & 31; \
            *(ushort4*)&Ab[buf][rr * PADK + kk] = ra[i]; \
        } \
        { int e = tid * 8; int rr = e >> 5, kk = e & 31; \
          *(ushort4*)&Bb[buf][rr * PADK + kk] = rb[0]; \
          *(ushort4*)&Bb[buf][rr * PADK + kk + 4] = rb[1]; } }

    PX_LOADA(0)
    PX_WRITE(0)
    __syncthreads();
    int cur = 0;
    for (int kt = 0; kt < 12; ++kt) {
        if (kt + 1 < 12) PX_LOADA((kt + 1) * BK)
        bf16x8 af[2], bfv[4];
#pragma unroll
        for (int m = 0; m < 2; ++m)
            af[m] = *(const bf16x8*)&Ab[cur][(wv * 32 + m * 16 + r16) * PADK + g * 8];
#pragma unroll
        for (int nn = 0; nn < 4; ++nn)
            bfv[nn] = *(const bf16x8*)&Bb[cur][(nn * 16 + r16) * PADK + g * 8];
#pragma unroll
        for (int m = 0; m < 2; ++m)
#pragma unroll
            for (int nn = 0; nn < 4; ++nn)
                acc[m][nn] = __builtin_amdgcn_mfma_f32_16x16x32_bf16(af[m], bfv[nn], acc[m][nn], 0, 0, 0);
        if (kt + 1 < 12) PX_WRITE(cur ^ 1)
        __syncthreads();
        cur ^= 1;
    }
#pragma unroll
    for (int m = 0; m < 2; ++m)
#pragma unroll
        for (int j = 0; j < 4; ++j) {
            int gr = bm + wv * 32 + m * 16 + g * 4 + j;
            if (gr >= N_NODES) continue;
#pragma unroll
            for (int nn = 0; nn < 4; ++nn)
                xb[(size_t)gr * 256 + z * 64 + nn * 16 + r16] = f2bf(elu_(acc[m][nn][j]));
        }
#undef PX_LOADA
#undef PX_WRITE
}

// ---------------- layer-2 score scalars ----------------
__global__ __launch_bounds__(256) void vsd2(const unsigned short* __restrict__ xb,
        const float* __restrict__ csd, float* __restrict__ vs2, float* __restrict__ vd2) {
    __shared__ float cs[512];
    int tid = threadIdx.x;
    for (int i = tid; i < 512; i += 256) cs[i] = csd[i];
    __syncthreads();
    int l = tid & 63, wv = tid >> 6;
    int n = blockIdx.x * 4 + wv;
    ushort4 u = *(const ushort4*)(xb + (size_t)n * 256 + 4 * l);
    float x0 = bf2f(u.x), x1 = bf2f(u.y), x2 = bf2f(u.z), x3 = bf2f(u.w);
    float ps = x0 * cs[4 * l] + x1 * cs[4 * l + 1] + x2 * cs[4 * l + 2] + x3 * cs[4 * l + 3];
    float pd = x0 * cs[256 + 4 * l] + x1 * cs[256 + 4 * l + 1] + x2 * cs[256 + 4 * l + 2] + x3 * cs[256 + 4 * l + 3];
#pragma unroll
    for (int off = 32; off; off >>= 1) { ps += __shfl_xor(ps, off); pd += __shfl_xor(pd, off); }
    if (l == 0) { vs2[n] = ps; vd2[n] = pd; }
}

// ---------------- layer-2 node aggregation: 2 waves/node ----------------
__global__ __launch_bounds__(256) void node_l2(const unsigned short* __restrict__ xb,
        const float* __restrict__ rel2t, const int* __restrict__ dord,
        const int* __restrict__ tord, const int* __restrict__ rowptr,
        const float* __restrict__ vs2, const float* __restrict__ vd2,
        const float* __restrict__ st2, unsigned short* __restrict__ accV,
        unsigned short* __restrict__ accRn) {
    __shared__ float comb[2][9][65];
    int tid = threadIdx.x, l = tid & 63, wv = tid >> 6;
    int slot = wv >> 1, h = wv & 1;
    int n = blockIdx.x * 2 + slot;
    int p0 = rowptr[n], p1 = rowptr[n + 1];
    float s0 = vs2[n];
    float aX[4] = {}, aR[4] = {};
    float rs = 0.f;
    ushort4 xv_n = make_ushort4(0, 0, 0, 0);
    float4 rt_n = make_float4(0.f, 0.f, 0.f, 0.f);
    float vdn_ = 0.f, stn_ = 0.f;
    int p = p0 + h;
    if (p < p1) {
        int d = dord[p], t = tord[p];
        xv_n = *(const ushort4*)(xb + (size_t)d * 256 + 4 * l);
        rt_n = *(const float4*)(rel2t + (size_t)t * 256 + 4 * l);
        vdn_ = vd2[d]; stn_ = st2[t];
    }
    for (; p < p1; p += 2) {
        ushort4 xv = xv_n; float4 rt = rt_n;
        float vdv = vdn_, stv = stn_;
        if (p + 2 < p1) {
            int d = dord[p + 2], t = tord[p + 2];
            xv_n = *(const ushort4*)(xb + (size_t)d * 256 + 4 * l);
            rt_n = *(const float4*)(rel2t + (size_t)t * 256 + 4 * l);
            vdn_ = vd2[d]; stn_ = st2[t];
        }
        float s = s0 + vdv + stv;
        s = s > 0.f ? s : ALPHA_ * s;
        float wgt = __expf(-s);
        rs += wgt;
        aX[0] = fmaf(wgt, bf2f(xv.x), aX[0]);
        aX[1] = fmaf(wgt, bf2f(xv.y), aX[1]);
        aX[2] = fmaf(wgt, bf2f(xv.z), aX[2]);
        aX[3] = fmaf(wgt, bf2f(xv.w), aX[3]);
        aR[0] = fmaf(wgt, rt.x, aR[0]);
        aR[1] = fmaf(wgt, rt.y, aR[1]);
        aR[2] = fmaf(wgt, rt.z, aR[2]);
        aR[3] = fmaf(wgt, rt.w, aR[3]);
    }
    float* cb = &comb[slot][0][l];
    if (h) {
#pragma unroll
        for (int k = 0; k < 4; ++k) {
            cb[k * 65] = aX[k];
            cb[(4 + k) * 65] = aR[k];
        }
        cb[8 * 65] = rs;
    }
    __syncthreads();
    if (!h) {
#pragma unroll
        for (int k = 0; k < 4; ++k) {
            aX[k] += cb[k * 65];
            aR[k] += cb[(4 + k) * 65];
        }
        rs += cb[8 * 65];
        float inv = 1.f / (rs + 1e-16f);
        unsigned short* vb = accV + (size_t)n * 512;
        ushort4 o;
        o.x = f2bf(aX[0] * inv); o.y = f2bf(aX[1] * inv);
        o.z = f2bf(aX[2] * inv); o.w = f2bf(aX[3] * inv);
        *(ushort4*)(vb + 4 * l) = o;
        ushort4 xn = *(const ushort4*)(xb + (size_t)n * 256 + 4 * l);
        if (p0 == p1) xn = make_ushort4(0, 0, 0, 0);
        *(ushort4*)(vb + 256 + 4 * l) = xn;
        ushort4 rn;
        rn.x = f2bf(aR[0] * inv); rn.y = f2bf(aR[1] * inv);
        rn.z = f2bf(aR[2] * inv); rn.w = f2bf(aR[3] * inv);
        *(ushort4*)(accRn + (size_t)n * 256 + 4 * l) = rn;
    }
}

// ---------------- final2: 2-phase dbuf; out = elu(accV @ B2^T + accRn) --------
__global__ __launch_bounds__(256) void final2(const unsigned short* __restrict__ accV,
        const unsigned short* __restrict__ B2, const unsigned short* __restrict__ accRn,
        float* __restrict__ out) {
    __shared__ unsigned short Ab[2][128 * PADK];
    __shared__ unsigned short Bb[2][128 * PADK];
    int tid = threadIdx.x, lane = tid & 63, wv = tid >> 6;
    int wr = wv >> 1, wc = wv & 1;
    int bm = blockIdx.y * 128, bn = blockIdx.x * 128;
    int r16 = lane & 15, g = lane >> 4;
    f32x4 acc[4][4] = {};
    ushort4 ra[4], rb[4];

#define F2_LOAD(k0) { \
        _Pragma("unroll") \
        for (int i = 0; i < 4; ++i) { \
            int e = i * 1024 + tid * 4; \
            int rr = e >> 5, kk = e & 31; \
            int gr = bm + rr; \
            ra[i] = (gr < N_NODES) ? *(const ushort4*)(accV + (size_t)gr * 512 + (k0) + kk) \
                                   : make_ushort4(0, 0, 0, 0); \
            rb[i] = *(const ushort4*)(B2 + (size_t)(bn + rr) * 512 + (k0) + kk); \
        } }

#define F2_WRITE(buf) { \
        _Pragma("unroll") \
        for (int i = 0; i < 4; ++i) { \
            int e = i * 1024 + tid * 4; \
            int rr = e >> 5, kk = e & 31; \
            *(ushort4*)&Ab[buf][rr * PADK + kk] = ra[i]; \
            *(ushort4*)&Bb[buf][rr * PADK + kk] = rb[i]; \
        } }

    F2_LOAD(0)
    F2_WRITE(0)
    __syncthreads();
    int cur = 0;
    for (int kt = 0; kt < 16; ++kt) {
        if (kt + 1 < 16) F2_LOAD((kt + 1) * BK)
        bf16x8 afrag[4], bfrag[4];
#pragma unroll
        for (int m = 0; m < 4; ++m)
            afrag[m] = *(const bf16x8*)&Ab[cur][(wr * 64 + m * 16 + r16) * PADK + g * 8];
#pragma unroll
        for (int nn = 0; nn < 4; ++nn)
            bfrag[nn] = *(const bf16x8*)&Bb[cur][(wc * 64 + nn * 16 + r16) * PADK + g * 8];
#pragma unroll
        for (int m = 0; m < 4; ++m)
#pragma unroll
            for (int nn = 0; nn < 4; ++nn)
                acc[m][nn] = __builtin_amdgcn_mfma_f32_16x16x32_bf16(afrag[m], bfrag[nn], acc[m][nn], 0, 0, 0);
        if (kt + 1 < 16) F2_WRITE(cur ^ 1)
        __syncthreads();
        cur ^= 1;
    }
#pragma unroll
    for (int m = 0; m < 4; ++m)
#pragma unroll
        for (int j = 0; j < 4; ++j) {
            int gr = bm + wr * 64 + m * 16 + g * 4 + j;
            if (gr >= N_NODES) continue;
#pragma unroll
            for (int nn = 0; nn < 4; ++nn) {
                int gc = bn + wc * 64 + nn * 16 + r16;
                out[(size_t)gr * 256 + gc] = elu_(acc[m][nn][j] + bf2f(accRn[(size_t)gr * 256 + gc]));
            }
        }
#undef F2_LOAD
#undef F2_WRITE
}

extern "C" void kernel_launch(void* const* d_in, const int* in_sizes, int n_in,
                              void* d_out, int out_size, void* d_ws, size_t ws_size,
                              hipStream_t stream) {
    const float* entity    = (const float*)d_in[0];
    const float* relemb    = (const float*)d_in[1];
    const float* edge_emb  = (const float*)d_in[2];
    const float* a_heads   = (const float*)d_in[3];
    const float* a2h       = (const float*)d_in[4];
    const float* a_out     = (const float*)d_in[5];
    const float* a2o       = (const float*)d_in[6];
    const float* W_1       = (const float*)d_in[7];
    const int*   elist     = (const int*)d_in[8];
    const int*   etype     = (const int*)d_in[9];
    const int*   src = elist;
    const int*   dst = elist + N_EDGES;
    float* out = (float*)d_out;

    char* ws = (char*)d_ws;
    size_t off = 0;
    auto alloc = [&](size_t bytes) -> void* {
        void* p = ws + off;
        off += (bytes + 255) & ~(size_t)255;
        return p;
    };
    float* rel2t   = (float*)alloc((size_t)N_REL * DIM2 * 4);
    float* cvec    = (float*)alloc(1536 * 4);
    float* csd     = (float*)alloc(512 * 4);
    float* st2     = (float*)alloc(N_REL * 4);
    float* vs      = (float*)alloc((size_t)N_NODES * 4 * 4);
    float* vd      = (float*)alloc((size_t)N_NODES * 4 * 4);
    float* vs2     = (float*)alloc((size_t)N_NODES * 4);
    float* vd2     = (float*)alloc((size_t)N_NODES * 4);
    float* w4p     = (float*)alloc((size_t)N_EDGES * 4 * 4);
    int*   deg     = (int*)alloc((size_t)N_NODES * 4);
    int*   rowptr  = (int*)alloc((size_t)(N_NODES + 1) * 4);
    int*   cur     = (int*)alloc((size_t)N_NODES * 4);
    int*   bsum    = (int*)alloc(128 * 4);
    int*   order   = (int*)alloc((size_t)N_EDGES * 4);
    int*   pos     = (int*)alloc((size_t)N_EDGES * 4);
    int*   dord    = (int*)alloc((size_t)N_EDGES * 4);
    int*   tord    = (int*)alloc((size_t)N_EDGES * 4);
    unsigned short* accU = (unsigned short*)alloc((size_t)N_NODES * 1152 * 2);
    unsigned short* B2   = (unsigned short*)alloc(256 * 512 * 2);
    unsigned short* BX   = (unsigned short*)alloc(256 * 384 * 2);
    unsigned short* xb    = (unsigned short*)alloc((size_t)N_NODES * 256 * 2);
    unsigned short* accV  = (unsigned short*)alloc((size_t)N_NODES * 512 * 2);
    unsigned short* accRn = (unsigned short*)alloc((size_t)N_NODES * 256 * 2);
    (void)ws_size; (void)in_sizes; (void)n_in; (void)out_size;

    // ---- weights / tables ----
    prep_all<<<512, 256, 0, stream>>>(a_heads, a_out, a2h, a2o, B2, BX, cvec, csd);
    rel2fused<<<N_REL, 256, 0, stream>>>(relemb, W_1, a_out, a2o, rel2t, st2);

    // ---- CSR build ----
    hipMemsetAsync(deg, 0, (size_t)N_NODES * 4, stream);
    histk<<<(N_EDGES + 255) / 256, 256, 0, stream>>>(src, deg);
    scan_part<<<NB_SCAN, 512, 0, stream>>>(deg, rowptr, bsum);
    scan_tops<<<1, 64, 0, stream>>>(bsum);
    scan_add<<<(N_NODES + 255) / 256, 256, 0, stream>>>(rowptr, bsum, cur);
    scatterk<<<(N_EDGES + 255) / 256, 256, 0, stream>>>(src, dst, etype, cur, order, pos, dord, tord);

    // ---- layer 1 ----
    gemv1<<<N_NODES / 4, 256, 0, stream>>>(entity, cvec, vs, vd);
    edge_w<<<(N_EDGES + 63) / 64, 256, 0, stream>>>(edge_emb, src, dst, pos, vs, vd, cvec, w4p);
    node_l1<<<N_NODES / 4, 256, 0, stream>>>(entity, edge_emb, w4p, order, dord, rowptr, accU);
    projx<<<dim3(4, (N_NODES + 127) / 128), 256, 0, stream>>>(accU, BX, xb);

    // ---- layer 2 ----
    vsd2<<<N_NODES / 4, 256, 0, stream>>>(xb, csd, vs2, vd2);
    node_l2<<<N_NODES / 2, 256, 0, stream>>>(xb, rel2t, dord, tord, rowptr,
                                             vs2, vd2, st2, accV, accRn);
    final2<<<dim3(2, (N_NODES + 127) / 128), 256, 0, stream>>>(accV, B2, accRn, out);
}